// Round 1
// baseline (579.933 us; speedup 1.0000x reference)
//
#include <hip/hip_runtime.h>
#include <math.h>

#define N_NODES 4000000
#define N_LINKS 8000000

// Physics constants (double-derived, stored as f32)
#define GACC        9.81f
#define RHO_I_G     8995.77f            // 917.0 * 9.81
#define RHO_W_G     9810.0f             // 1000.0 * 9.81
#define NU_W        1.787e-6f
#define OMEGA_F     1e-3f
#define LHEAT_INV   (1.0f / 334000.0f)
#define AFLU        6e-24f
#define U0_F        50.0f
#define TAN_PHI     0.6248693519093275f // tan(deg2rad(32.0))
#define C_MELT      (-9.051253950474704e-05f) // 1/1000 - 1/917
#define TCOEF       (9.81f / (12.0f * 1.787e-6f))

// ---------------- Kernel 1: per-link grad_h, Q, pack {grad,Q,u,0} ----------------
__global__ __launch_bounds__(256) void link_kernel(
    const float* __restrict__ conduit,
    const float* __restrict__ reynolds,
    const float* __restrict__ u_ice,
    const float* __restrict__ length,
    const float* __restrict__ h,
    const int*   __restrict__ head,
    const int*   __restrict__ tail,
    float4*      __restrict__ pack,
    int L)
{
    int i = blockIdx.x * blockDim.x + threadIdx.x;
    int stride = gridDim.x * blockDim.x;
    for (; i < L; i += stride) {
        int hi = head[i];
        int ti = tail[i];
        float hh = h[hi];
        float ht = h[ti];
        float gh = (hh - ht) / length[i];
        float c  = conduit[i];
        float T  = (c * c * c) * TCOEF / (1.0f + OMEGA_F * reynolds[i]);
        float Q  = -T * gh;
        pack[i] = make_float4(gh, Q, u_ice[i], 0.0f);
    }
}

// ---------------- Kernel 2: per-node assembly (packed gathers) ----------------
__global__ __launch_bounds__(256) void node_kernel(
    const float*  __restrict__ h,
    const float*  __restrict__ thick,
    const float*  __restrict__ bed,
    const float*  __restrict__ melt_in,
    const float*  __restrict__ geo,
    const float*  __restrict__ area,
    const float4* __restrict__ dirs,   // [N] rows of 4
    const int4*   __restrict__ links,  // [N] rows of 4
    const float4* __restrict__ pack,   // {grad, Q, u, 0} per link
    float*        __restrict__ out,
    int N)
{
    int i = blockIdx.x * blockDim.x + threadIdx.x;
    int stride = gridDim.x * blockDim.x;
    for (; i < N; i += stride) {
        int4   ln = links[i];
        float4 p0 = pack[ln.x];
        float4 p1 = pack[ln.y];
        float4 p2 = pack[ln.z];
        float4 p3 = pack[ln.w];
        float4 d  = dirs[i];

        float hv = h[i];
        float ob = RHO_I_G * thick[i];
        float pw = fminf((hv - bed[i]) * RHO_W_G, ob);
        float Neff = ob - pw;

        float u_node    = 0.25f * (p0.z + p1.z + p2.z + p3.z);
        float grad_node = 0.25f * (p0.x + p1.x + p2.x + p3.x);
        float Q_node    = 0.25f * (p0.y + p1.y + p2.y + p3.y);

        float uabs = fabsf(u_node);
        float tau  = Neff * TAN_PHI * powf(uabs / (uabs + U0_F), 0.2f);
        float frictional  = fabsf(u_node * tau);
        float dissipation = RHO_W_G * Q_node * grad_node;
        float melt_rate   = (geo[i] + frictional - dissipation) * LHEAT_INV;

        float flux_term = (d.x * p0.y + d.y * p1.y + d.z * p2.y + d.w * p3.y) / area[i];
        float melt_term = -melt_rate * C_MELT;
        float Ne3 = Neff * Neff * Neff;
        float closure_term = -AFLU * Ne3 * hv;

        out[i] = flux_term - melt_term - closure_term - melt_in[i] + hv;
    }
}

// ---------------- Fallback: fully fused (no workspace) ----------------
__global__ __launch_bounds__(256) void node_kernel_fused(
    const float* __restrict__ conduit,
    const float* __restrict__ reynolds,
    const float* __restrict__ u_ice,
    const float* __restrict__ length,
    const float* __restrict__ h,
    const float* __restrict__ thick,
    const float* __restrict__ bed,
    const float* __restrict__ melt_in,
    const float* __restrict__ geo,
    const float* __restrict__ area,
    const float4* __restrict__ dirs,
    const int4*  __restrict__ links,
    const int*   __restrict__ head,
    const int*   __restrict__ tail,
    float*       __restrict__ out,
    int N)
{
    int i = blockIdx.x * blockDim.x + threadIdx.x;
    int stride = gridDim.x * blockDim.x;
    for (; i < N; i += stride) {
        int4   ln = links[i];
        float4 d  = dirs[i];
        int lid[4] = {ln.x, ln.y, ln.z, ln.w};
        float dd[4] = {d.x, d.y, d.z, d.w};

        float u_sum = 0.f, g_sum = 0.f, q_sum = 0.f, flux_sum = 0.f;
        #pragma unroll
        for (int j = 0; j < 4; ++j) {
            int l = lid[j];
            float gh = (h[head[l]] - h[tail[l]]) / length[l];
            float c  = conduit[l];
            float T  = (c * c * c) * TCOEF / (1.0f + OMEGA_F * reynolds[l]);
            float Q  = -T * gh;
            u_sum += u_ice[l];
            g_sum += gh;
            q_sum += Q;
            flux_sum += dd[j] * Q;
        }

        float hv = h[i];
        float ob = RHO_I_G * thick[i];
        float pw = fminf((hv - bed[i]) * RHO_W_G, ob);
        float Neff = ob - pw;

        float u_node    = 0.25f * u_sum;
        float grad_node = 0.25f * g_sum;
        float Q_node    = 0.25f * q_sum;

        float uabs = fabsf(u_node);
        float tau  = Neff * TAN_PHI * powf(uabs / (uabs + U0_F), 0.2f);
        float frictional  = fabsf(u_node * tau);
        float dissipation = RHO_W_G * Q_node * grad_node;
        float melt_rate   = (geo[i] + frictional - dissipation) * LHEAT_INV;

        float flux_term = flux_sum / area[i];
        float melt_term = -melt_rate * C_MELT;
        float Ne3 = Neff * Neff * Neff;
        float closure_term = -AFLU * Ne3 * hv;

        out[i] = flux_term - melt_term - closure_term - melt_in[i] + hv;
    }
}

extern "C" void kernel_launch(void* const* d_in, const int* in_sizes, int n_in,
                              void* d_out, int out_size, void* d_ws, size_t ws_size,
                              hipStream_t stream) {
    const float* conduit  = (const float*)d_in[0];
    const float* reynolds = (const float*)d_in[1];
    const float* u_ice    = (const float*)d_in[2];
    const float* length   = (const float*)d_in[3];
    const float* h        = (const float*)d_in[4];
    const float* thick    = (const float*)d_in[5];
    const float* bed      = (const float*)d_in[6];
    const float* melt_in  = (const float*)d_in[7];
    const float* geo      = (const float*)d_in[8];
    const float* area     = (const float*)d_in[9];
    const float4* dirs    = (const float4*)d_in[10];
    const int*   head     = (const int*)d_in[11];
    const int*   tail     = (const int*)d_in[12];
    const int4*  links    = (const int4*)d_in[13];

    float* out = (float*)d_out;
    const int L = in_sizes[0];   // 8M
    const int N = in_sizes[4];   // 4M

    const size_t pack_bytes = (size_t)L * sizeof(float4);

    if (ws_size >= pack_bytes) {
        float4* pack = (float4*)d_ws;
        {
            int threads = 256;
            int blocks = (L + threads - 1) / threads;
            if (blocks > 8192) blocks = 8192;
            link_kernel<<<blocks, threads, 0, stream>>>(
                conduit, reynolds, u_ice, length, h, head, tail, pack, L);
        }
        {
            int threads = 256;
            int blocks = (N + threads - 1) / threads;
            if (blocks > 8192) blocks = 8192;
            node_kernel<<<blocks, threads, 0, stream>>>(
                h, thick, bed, melt_in, geo, area, dirs, links, pack, out, N);
        }
    } else {
        int threads = 256;
        int blocks = (N + threads - 1) / threads;
        if (blocks > 8192) blocks = 8192;
        node_kernel_fused<<<blocks, threads, 0, stream>>>(
            conduit, reynolds, u_ice, length, h, thick, bed, melt_in, geo, area,
            dirs, links, head, tail, out, N);
    }
}

// Round 2
// 551.909 us; speedup vs baseline: 1.0508x; 1.0508x over previous
//
#include <hip/hip_runtime.h>
#include <math.h>

#define GACC        9.81f
#define RHO_I_G     8995.77f            // 917.0 * 9.81
#define RHO_W_G     9810.0f             // 1000.0 * 9.81
#define OMEGA_F     1e-3f
#define LHEAT_INV   (1.0f / 334000.0f)
#define AFLU        6e-24f
#define U0_F        50.0f
#define TAN_PHI     0.6248693519093275f // tan(deg2rad(32.0))
#define C_MELT      (-9.051253950474704e-05f) // 1/1000 - 1/917
#define TCOEF       (9.81f / (12.0f * 1.787e-6f))

// round-to-nearest-even f32 -> bf16 bits (low 16)
static __device__ __forceinline__ unsigned int bf16r(float x) {
    unsigned int b = __builtin_bit_cast(unsigned int, x);
    return (b + 0x7FFFu + ((b >> 16) & 1u)) >> 16;
}
static __device__ __forceinline__ float bf16_lo_to_f32(unsigned int w) {
    return __builtin_bit_cast(float, w << 16);        // low 16 bits are the bf16
}
static __device__ __forceinline__ float bf16_hi_to_f32(unsigned int w) {
    return __builtin_bit_cast(float, w & 0xFFFF0000u); // high 16 bits are the bf16
}

// ---------------- Kernel 1: per-link grad_h, Q, pack {Q:f32, grad:bf16, u:bf16} = 8B ----------------
__global__ __launch_bounds__(256) void link_kernel(
    const float* __restrict__ conduit,
    const float* __restrict__ reynolds,
    const float* __restrict__ u_ice,
    const float* __restrict__ length,
    const float* __restrict__ h,
    const int*   __restrict__ head,
    const int*   __restrict__ tail,
    uint2*       __restrict__ pack,
    int L)
{
    int i = blockIdx.x * blockDim.x + threadIdx.x;
    if (i >= L) return;

    int hi = head[i];
    int ti = tail[i];
    float hh = h[hi];
    float ht = h[ti];
    float gh = (hh - ht) / length[i];
    float c  = conduit[i];
    float T  = (c * c * c) * TCOEF / (1.0f + OMEGA_F * reynolds[i]);
    float Q  = -T * gh;

    uint2 pk;
    pk.x = __builtin_bit_cast(unsigned int, Q);
    pk.y = bf16r(gh) | (bf16r(u_ice[i]) << 16);
    pack[i] = pk;
}

// ---------------- Kernel 2: per-node assembly (8B packed gathers) ----------------
__global__ __launch_bounds__(256) void node_kernel(
    const float*  __restrict__ h,
    const float*  __restrict__ thick,
    const float*  __restrict__ bed,
    const float*  __restrict__ melt_in,
    const float*  __restrict__ geo,
    const float*  __restrict__ area,
    const float4* __restrict__ dirs,   // [N] rows of 4
    const int4*   __restrict__ links,  // [N] rows of 4
    const uint2*  __restrict__ pack,   // {Q, grad|u<<16} per link
    float*        __restrict__ out,
    int N)
{
    int i = blockIdx.x * blockDim.x + threadIdx.x;
    if (i >= N) return;

    int4  ln = links[i];
    uint2 p0 = pack[ln.x];
    uint2 p1 = pack[ln.y];
    uint2 p2 = pack[ln.z];
    uint2 p3 = pack[ln.w];
    float4 d = dirs[i];

    float Q0 = __builtin_bit_cast(float, p0.x);
    float Q1 = __builtin_bit_cast(float, p1.x);
    float Q2 = __builtin_bit_cast(float, p2.x);
    float Q3 = __builtin_bit_cast(float, p3.x);

    float hv = h[i];
    float ob = RHO_I_G * thick[i];
    float pw = fminf((hv - bed[i]) * RHO_W_G, ob);
    float Neff = ob - pw;

    float u_node    = 0.25f * (bf16_hi_to_f32(p0.y) + bf16_hi_to_f32(p1.y) +
                               bf16_hi_to_f32(p2.y) + bf16_hi_to_f32(p3.y));
    float grad_node = 0.25f * (bf16_lo_to_f32(p0.y) + bf16_lo_to_f32(p1.y) +
                               bf16_lo_to_f32(p2.y) + bf16_lo_to_f32(p3.y));
    float Q_node    = 0.25f * (Q0 + Q1 + Q2 + Q3);

    float uabs = fabsf(u_node);
    float tau  = Neff * TAN_PHI * powf(uabs / (uabs + U0_F), 0.2f);
    float frictional  = fabsf(u_node * tau);
    float dissipation = RHO_W_G * Q_node * grad_node;
    float melt_rate   = (geo[i] + frictional - dissipation) * LHEAT_INV;

    float flux_term = (d.x * Q0 + d.y * Q1 + d.z * Q2 + d.w * Q3) / area[i];
    float melt_term = -melt_rate * C_MELT;
    float Ne3 = Neff * Neff * Neff;
    float closure_term = -AFLU * Ne3 * hv;

    out[i] = flux_term - melt_term - closure_term - melt_in[i] + hv;
}

// ---------------- Fallback: fully fused (no workspace) ----------------
__global__ __launch_bounds__(256) void node_kernel_fused(
    const float* __restrict__ conduit,
    const float* __restrict__ reynolds,
    const float* __restrict__ u_ice,
    const float* __restrict__ length,
    const float* __restrict__ h,
    const float* __restrict__ thick,
    const float* __restrict__ bed,
    const float* __restrict__ melt_in,
    const float* __restrict__ geo,
    const float* __restrict__ area,
    const float4* __restrict__ dirs,
    const int4*  __restrict__ links,
    const int*   __restrict__ head,
    const int*   __restrict__ tail,
    float*       __restrict__ out,
    int N)
{
    int i = blockIdx.x * blockDim.x + threadIdx.x;
    int stride = gridDim.x * blockDim.x;
    for (; i < N; i += stride) {
        int4   ln = links[i];
        float4 d  = dirs[i];
        int lid[4] = {ln.x, ln.y, ln.z, ln.w};
        float dd[4] = {d.x, d.y, d.z, d.w};

        float u_sum = 0.f, g_sum = 0.f, q_sum = 0.f, flux_sum = 0.f;
        #pragma unroll
        for (int j = 0; j < 4; ++j) {
            int l = lid[j];
            float gh = (h[head[l]] - h[tail[l]]) / length[l];
            float c  = conduit[l];
            float T  = (c * c * c) * TCOEF / (1.0f + OMEGA_F * reynolds[l]);
            float Q  = -T * gh;
            u_sum += u_ice[l];
            g_sum += gh;
            q_sum += Q;
            flux_sum += dd[j] * Q;
        }

        float hv = h[i];
        float ob = RHO_I_G * thick[i];
        float pw = fminf((hv - bed[i]) * RHO_W_G, ob);
        float Neff = ob - pw;

        float u_node    = 0.25f * u_sum;
        float grad_node = 0.25f * g_sum;
        float Q_node    = 0.25f * q_sum;

        float uabs = fabsf(u_node);
        float tau  = Neff * TAN_PHI * powf(uabs / (uabs + U0_F), 0.2f);
        float frictional  = fabsf(u_node * tau);
        float dissipation = RHO_W_G * Q_node * grad_node;
        float melt_rate   = (geo[i] + frictional - dissipation) * LHEAT_INV;

        float flux_term = flux_sum / area[i];
        float melt_term = -melt_rate * C_MELT;
        float Ne3 = Neff * Neff * Neff;
        float closure_term = -AFLU * Ne3 * hv;

        out[i] = flux_term - melt_term - closure_term - melt_in[i] + hv;
    }
}

extern "C" void kernel_launch(void* const* d_in, const int* in_sizes, int n_in,
                              void* d_out, int out_size, void* d_ws, size_t ws_size,
                              hipStream_t stream) {
    const float* conduit  = (const float*)d_in[0];
    const float* reynolds = (const float*)d_in[1];
    const float* u_ice    = (const float*)d_in[2];
    const float* length   = (const float*)d_in[3];
    const float* h        = (const float*)d_in[4];
    const float* thick    = (const float*)d_in[5];
    const float* bed      = (const float*)d_in[6];
    const float* melt_in  = (const float*)d_in[7];
    const float* geo      = (const float*)d_in[8];
    const float* area     = (const float*)d_in[9];
    const float4* dirs    = (const float4*)d_in[10];
    const int*   head     = (const int*)d_in[11];
    const int*   tail     = (const int*)d_in[12];
    const int4*  links    = (const int4*)d_in[13];

    float* out = (float*)d_out;
    const int L = in_sizes[0];   // 8M
    const int N = in_sizes[4];   // 4M

    const size_t pack_bytes = (size_t)L * sizeof(uint2);

    if (ws_size >= pack_bytes) {
        uint2* pack = (uint2*)d_ws;
        {
            int threads = 256;
            int blocks = (L + threads - 1) / threads;   // full grid: max wave parallelism
            link_kernel<<<blocks, threads, 0, stream>>>(
                conduit, reynolds, u_ice, length, h, head, tail, pack, L);
        }
        {
            int threads = 256;
            int blocks = (N + threads - 1) / threads;
            node_kernel<<<blocks, threads, 0, stream>>>(
                h, thick, bed, melt_in, geo, area, dirs, links, pack, out, N);
        }
    } else {
        int threads = 256;
        int blocks = (N + threads - 1) / threads;
        if (blocks > 8192) blocks = 8192;
        node_kernel_fused<<<blocks, threads, 0, stream>>>(
            conduit, reynolds, u_ice, length, h, thick, bed, melt_in, geo, area,
            dirs, links, head, tail, out, N);
    }
}

// Round 3
// 543.139 us; speedup vs baseline: 1.0677x; 1.0161x over previous
//
#include <hip/hip_runtime.h>
#include <math.h>

#define RHO_I_G     8995.77f            // 917.0 * 9.81
#define RHO_W_G     9810.0f             // 1000.0 * 9.81
#define OMEGA_F     1e-3f
#define LHEAT_INV   (1.0f / 334000.0f)
#define AFLU        6e-24f
#define U0_F        50.0f
#define TAN_PHI     0.6248693519093275f // tan(deg2rad(32.0))
#define C_MELT      (-9.051253950474704e-05f) // 1/1000 - 1/917
#define TCOEF       (9.81f / (12.0f * 1.787e-6f))

typedef float f32x4 __attribute__((ext_vector_type(4)));
typedef int   i32x4 __attribute__((ext_vector_type(4)));

// round-to-nearest-even f32 -> bf16 bits (low 16)
static __device__ __forceinline__ unsigned int bf16r(float x) {
    unsigned int b = __builtin_bit_cast(unsigned int, x);
    return (b + 0x7FFFu + ((b >> 16) & 1u)) >> 16;
}
static __device__ __forceinline__ float bf16_lo_to_f32(unsigned int w) {
    return __builtin_bit_cast(float, w << 16);
}
static __device__ __forceinline__ float bf16_hi_to_f32(unsigned int w) {
    return __builtin_bit_cast(float, w & 0xFFFF0000u);
}

// ---------------- Kernel 1: per-link grad_h, Q, pack {Q:f32, grad:bf16|u:bf16} = 8B ----------------
__global__ __launch_bounds__(256) void link_kernel(
    const float* __restrict__ conduit,
    const float* __restrict__ reynolds,
    const float* __restrict__ u_ice,
    const float* __restrict__ length,
    const float* __restrict__ h,
    const int*   __restrict__ head,
    const int*   __restrict__ tail,
    uint2*       __restrict__ pack,
    int L)
{
    int i = blockIdx.x * blockDim.x + threadIdx.x;
    if (i >= L) return;

    // zero-reuse streams: non-temporal so they don't evict h from L2/L3
    int   hi = __builtin_nontemporal_load(head + i);
    int   ti = __builtin_nontemporal_load(tail + i);
    float ln = __builtin_nontemporal_load(length + i);
    float c  = __builtin_nontemporal_load(conduit + i);
    float re = __builtin_nontemporal_load(reynolds + i);
    float u  = __builtin_nontemporal_load(u_ice + i);

    // gathers into 16 MB h table: keep cached
    float hh = h[hi];
    float ht = h[ti];

    float gh = (hh - ht) / ln;
    float T  = (c * c * c) * TCOEF / (1.0f + OMEGA_F * re);
    float Q  = -T * gh;

    uint2 pk;
    pk.x = __builtin_bit_cast(unsigned int, Q);
    pk.y = bf16r(gh) | (bf16r(u) << 16);
    pack[i] = pk;   // regular store: we WANT this L3-resident for kernel 2
}

// ---------------- Kernel 2: per-node assembly (8B packed gathers) ----------------
__global__ __launch_bounds__(256) void node_kernel(
    const float*  __restrict__ h,
    const float*  __restrict__ thick,
    const float*  __restrict__ bed,
    const float*  __restrict__ melt_in,
    const float*  __restrict__ geo,
    const float*  __restrict__ area,
    const float*  __restrict__ dirs,   // [N,4]
    const int*    __restrict__ links,  // [N,4]
    const uint2*  __restrict__ pack,   // {Q, grad|u<<16} per link
    float*        __restrict__ out,
    int N)
{
    int i = blockIdx.x * blockDim.x + threadIdx.x;
    if (i >= N) return;

    // zero-reuse streams: non-temporal so the pack table stays L3-resident
    i32x4 ln4 = __builtin_nontemporal_load((const i32x4*)(links) + i);
    f32x4 d   = __builtin_nontemporal_load((const f32x4*)(dirs) + i);
    float hv  = __builtin_nontemporal_load(h + i);
    float th  = __builtin_nontemporal_load(thick + i);
    float bd  = __builtin_nontemporal_load(bed + i);
    float mi  = __builtin_nontemporal_load(melt_in + i);
    float ge  = __builtin_nontemporal_load(geo + i);
    float ar  = __builtin_nontemporal_load(area + i);

    // random gathers into 64 MB pack table: keep cached
    uint2 p0 = pack[ln4.x];
    uint2 p1 = pack[ln4.y];
    uint2 p2 = pack[ln4.z];
    uint2 p3 = pack[ln4.w];

    float Q0 = __builtin_bit_cast(float, p0.x);
    float Q1 = __builtin_bit_cast(float, p1.x);
    float Q2 = __builtin_bit_cast(float, p2.x);
    float Q3 = __builtin_bit_cast(float, p3.x);

    float ob = RHO_I_G * th;
    float pw = fminf((hv - bd) * RHO_W_G, ob);
    float Neff = ob - pw;

    float u_node    = 0.25f * (bf16_hi_to_f32(p0.y) + bf16_hi_to_f32(p1.y) +
                               bf16_hi_to_f32(p2.y) + bf16_hi_to_f32(p3.y));
    float grad_node = 0.25f * (bf16_lo_to_f32(p0.y) + bf16_lo_to_f32(p1.y) +
                               bf16_lo_to_f32(p2.y) + bf16_lo_to_f32(p3.y));
    float Q_node    = 0.25f * (Q0 + Q1 + Q2 + Q3);

    float uabs = fabsf(u_node);
    float tau  = Neff * TAN_PHI * powf(uabs / (uabs + U0_F), 0.2f);
    float frictional  = fabsf(u_node * tau);
    float dissipation = RHO_W_G * Q_node * grad_node;
    float melt_rate   = (ge + frictional - dissipation) * LHEAT_INV;

    float flux_term = (d.x * Q0 + d.y * Q1 + d.z * Q2 + d.w * Q3) / ar;
    float melt_term = -melt_rate * C_MELT;
    float Ne3 = Neff * Neff * Neff;
    float closure_term = -AFLU * Ne3 * hv;

    float result = flux_term - melt_term - closure_term - mi + hv;
    __builtin_nontemporal_store(result, out + i);
}

// ---------------- Fallback: fully fused (no workspace) ----------------
__global__ __launch_bounds__(256) void node_kernel_fused(
    const float* __restrict__ conduit,
    const float* __restrict__ reynolds,
    const float* __restrict__ u_ice,
    const float* __restrict__ length,
    const float* __restrict__ h,
    const float* __restrict__ thick,
    const float* __restrict__ bed,
    const float* __restrict__ melt_in,
    const float* __restrict__ geo,
    const float* __restrict__ area,
    const float4* __restrict__ dirs,
    const int4*  __restrict__ links,
    const int*   __restrict__ head,
    const int*   __restrict__ tail,
    float*       __restrict__ out,
    int N)
{
    int i = blockIdx.x * blockDim.x + threadIdx.x;
    int stride = gridDim.x * blockDim.x;
    for (; i < N; i += stride) {
        int4   ln = links[i];
        float4 d  = dirs[i];
        int lid[4] = {ln.x, ln.y, ln.z, ln.w};
        float dd[4] = {d.x, d.y, d.z, d.w};

        float u_sum = 0.f, g_sum = 0.f, q_sum = 0.f, flux_sum = 0.f;
        #pragma unroll
        for (int j = 0; j < 4; ++j) {
            int l = lid[j];
            float gh = (h[head[l]] - h[tail[l]]) / length[l];
            float c  = conduit[l];
            float T  = (c * c * c) * TCOEF / (1.0f + OMEGA_F * reynolds[l]);
            float Q  = -T * gh;
            u_sum += u_ice[l];
            g_sum += gh;
            q_sum += Q;
            flux_sum += dd[j] * Q;
        }

        float hv = h[i];
        float ob = RHO_I_G * thick[i];
        float pw = fminf((hv - bed[i]) * RHO_W_G, ob);
        float Neff = ob - pw;

        float u_node    = 0.25f * u_sum;
        float grad_node = 0.25f * g_sum;
        float Q_node    = 0.25f * q_sum;

        float uabs = fabsf(u_node);
        float tau  = Neff * TAN_PHI * powf(uabs / (uabs + U0_F), 0.2f);
        float frictional  = fabsf(u_node * tau);
        float dissipation = RHO_W_G * Q_node * grad_node;
        float melt_rate   = (geo[i] + frictional - dissipation) * LHEAT_INV;

        float flux_term = flux_sum / area[i];
        float melt_term = -melt_rate * C_MELT;
        float Ne3 = Neff * Neff * Neff;
        float closure_term = -AFLU * Ne3 * hv;

        out[i] = flux_term - melt_term - closure_term - melt_in[i] + hv;
    }
}

extern "C" void kernel_launch(void* const* d_in, const int* in_sizes, int n_in,
                              void* d_out, int out_size, void* d_ws, size_t ws_size,
                              hipStream_t stream) {
    const float* conduit  = (const float*)d_in[0];
    const float* reynolds = (const float*)d_in[1];
    const float* u_ice    = (const float*)d_in[2];
    const float* length   = (const float*)d_in[3];
    const float* h        = (const float*)d_in[4];
    const float* thick    = (const float*)d_in[5];
    const float* bed      = (const float*)d_in[6];
    const float* melt_in  = (const float*)d_in[7];
    const float* geo      = (const float*)d_in[8];
    const float* area     = (const float*)d_in[9];
    const float* dirs     = (const float*)d_in[10];
    const int*   head     = (const int*)d_in[11];
    const int*   tail     = (const int*)d_in[12];
    const int*   links    = (const int*)d_in[13];

    float* out = (float*)d_out;
    const int L = in_sizes[0];   // 8M
    const int N = in_sizes[4];   // 4M

    const size_t pack_bytes = (size_t)L * sizeof(uint2);

    if (ws_size >= pack_bytes) {
        uint2* pack = (uint2*)d_ws;
        {
            int threads = 256;
            int blocks = (L + threads - 1) / threads;
            link_kernel<<<blocks, threads, 0, stream>>>(
                conduit, reynolds, u_ice, length, h, head, tail, pack, L);
        }
        {
            int threads = 256;
            int blocks = (N + threads - 1) / threads;
            node_kernel<<<blocks, threads, 0, stream>>>(
                h, thick, bed, melt_in, geo, area, dirs, links, pack, out, N);
        }
    } else {
        int threads = 256;
        int blocks = (N + threads - 1) / threads;
        if (blocks > 8192) blocks = 8192;
        node_kernel_fused<<<blocks, threads, 0, stream>>>(
            conduit, reynolds, u_ice, length, h, thick, bed, melt_in, geo, area,
            (const float4*)dirs, (const int4*)links, head, tail, out, N);
    }
}